// Round 7
// baseline (192.658 us; speedup 1.0000x reference)
//
#include <hip/hip_runtime.h>

#define Bn 512
#define Tn 512
#define Cn 64

// Inputs (setup_inputs order):
// 0: emissions (B,T,C) f32   1: tags (B,T) i32   2: mask (B,T) i32
// 3: transitions (C,C) f32   4: start_transitions (C) f32   5: end_transitions (C) f32
// Output: scalar f32 = mean_b(log_denominator - log_numerator)
//
// R6b: meet-in-the-middle (depth 511->256, validated R5) + f16-packed dot:
// 32x v_readlane of packed (alpha[2m],alpha[2m+1]) halves + 32x
// v_dot2_f32_f16 (fp32 accumulate) instead of 64 readlane + 64 fma.
// f16 range forces renorm EVERY step (wave-max DPP, uniform scale = exact).
// No atomics: single-block finalize kernel.
// NOTE: __builtin_amdgcn_cvt_pkrtz / _fdot2 use __fp16 ext-vector, not _Float16.

typedef __fp16 half2_t __attribute__((ext_vector_type(2)));

__device__ __forceinline__ half2_t int_as_half2(int x) {
    union { int i; half2_t h; } u; u.i = x; return u.h;
}
__device__ __forceinline__ int half2_as_int(half2_t h) {
    union { int i; half2_t h; } u; u.h = h; return u.i;
}

template <int CTRL>
__device__ __forceinline__ float fmax_dpp(const float v) {
    const int o = __builtin_amdgcn_update_dpp(__float_as_int(v), __float_as_int(v),
                                              CTRL, 0xF, 0xF, false);
    return fmaxf(v, __int_as_float(o));
}
template <int CTRL>
__device__ __forceinline__ float mov_dpp(const float v) {
    return __int_as_float(__builtin_amdgcn_update_dpp(
        __float_as_int(v), __float_as_int(v), CTRL, 0xF, 0xF, false));
}

// Validated wave64 max (R2-R5): lane 63 holds the max; readlane broadcasts.
__device__ __forceinline__ float wave_max64(float v) {
    v = fmax_dpp<0x0B1>(v);
    v = fmax_dpp<0x04E>(v);
    v = fmax_dpp<0x141>(v);
    v = fmax_dpp<0x140>(v);
    v = fmax_dpp<0x142>(v);
    v = fmax_dpp<0x143>(v);
    return __int_as_float(__builtin_amdgcn_readlane(__float_as_int(v), 63));
}

// Pack (x[2m], x[2m+1]) as f16 pair, identical on both lanes of the pair:
// neighbor via quad_perm xor1, then order by lane parity, cvt_pkrtz.
__device__ __forceinline__ int pack_pair_f16(const float s, const bool odd) {
    const float nb = mov_dpp<0x0B1>(s);
    const float lo = odd ? nb : s;
    const float hi = odd ? s  : nb;
    return half2_as_int(__builtin_amdgcn_cvt_pkrtz(lo, hi));
}

// blocks 0..511: forward chain bt (steps t=1..256) + numerator.
// blocks 512..1023: backward chain bt (factors u=511..257, 255 steps).
__global__ __launch_bounds__(64) void crf_half_kernel(
    const float* __restrict__ emissions,
    const int*   __restrict__ tags,
    const int*   __restrict__ mask,
    const float* __restrict__ transitions,
    const float* __restrict__ start_t,
    const float* __restrict__ end_t,
    float*       __restrict__ ws_alpha,   // [Bn][Cn]
    float*       __restrict__ ws_beta,    // [Bn][Cn]
    float*       __restrict__ ws_lsF,     // [Bn]
    float*       __restrict__ ws_lsB,     // [Bn]
    float*       __restrict__ ws_num)     // [Bn]
{
    const int  blk = blockIdx.x;
    const bool fwd = blk < Bn;
    const int  bt  = blk & (Bn - 1);
    const int  j   = threadIdx.x;
    const bool odd = j & 1;

    const float* em  = emissions + (size_t)bt * Tn * Cn + j;
    const float* em0 = emissions + (size_t)bt * Tn * Cn;
    const int*   mk  = mask + bt * Tn;
    const int*   tg  = tags + bt * Tn;

    if (fwd) {
        // ---------------- numerator (joint score), lanes stride over T -----
        float nsum = 0.f;
        int   mcnt = 0;
        for (int t = j; t < Tn; t += 64) {
            const int tag_t = tg[t];
            const int m_t   = mk[t];
            mcnt += m_t;
            if (t >= 1 && m_t) {
                const int tag_p = tg[t - 1];
                nsum += transitions[tag_p * Cn + tag_t] + em0[t * Cn + tag_t];
            }
        }
#pragma unroll
        for (int off = 32; off > 0; off >>= 1) {
            nsum += __shfl_xor(nsum, off, 64);
            mcnt += __shfl_xor(mcnt, off, 64);
        }

        // expT column j as 32 packed f16 pairs (pair over source state i).
        half2_t w2[32];
#pragma unroll
        for (int m = 0; m < 32; ++m) {
            const float w0 = __expf(transitions[(2 * m) * Cn + j]);
            const float w1 = __expf(transitions[(2 * m + 1) * Cn + j]);
            w2[m] = __builtin_amdgcn_cvt_pkrtz(w0, w1);
        }

        // t = 0.
        float lp0 = start_t[j] + em[0];
        const float m0 = wave_max64(lp0);
        float log_scale = m0;
        float a_self = __expf(lp0 - m0);       // lane j holds alpha[j] <= 1
        int   a_pk   = pack_pair_f16(a_self, odd);

        // Prefetch group 0 (t = 1..4).
        float cur_e[4];
        int   cur_m[4];
#pragma unroll
        for (int k = 0; k < 4; ++k) {
            cur_e[k] = em[(size_t)(1 + k) * Cn];
            cur_m[k] = mk[1 + k];
        }

        for (int g = 0; g < 64; ++g) {         // 64 groups x 4 = 256 steps
            float nxt_e[4];
            int   nxt_m[4];
#pragma unroll
            for (int k = 0; k < 4; ++k) {
                const int t = 4 * g + 5 + k;   // <= 260 < Tn, always valid
                nxt_e[k] = em[(size_t)t * Cn];
                nxt_m[k] = mk[t];
            }
            float ex[4];
#pragma unroll
            for (int k = 0; k < 4; ++k) ex[k] = __expf(cur_e[k]);

#pragma unroll
            for (int k = 0; k < 4; ++k) {
                // Broadcast packed alpha pairs into SGPRs (32 readlanes).
                int au[32];
#pragma unroll
                for (int m = 0; m < 32; ++m)
                    au[m] = __builtin_amdgcn_readlane(a_pk, 2 * m);

                float acc0 = 0.f, acc1 = 0.f, acc2 = 0.f, acc3 = 0.f;
#pragma unroll
                for (int m = 0; m < 32; m += 4) {
                    acc0 = __builtin_amdgcn_fdot2(int_as_half2(au[m + 0]), w2[m + 0], acc0, false);
                    acc1 = __builtin_amdgcn_fdot2(int_as_half2(au[m + 1]), w2[m + 1], acc1, false);
                    acc2 = __builtin_amdgcn_fdot2(int_as_half2(au[m + 2]), w2[m + 2], acc2, false);
                    acc3 = __builtin_amdgcn_fdot2(int_as_half2(au[m + 3]), w2[m + 3], acc3, false);
                }
                float s = ((acc0 + acc1) + (acc2 + acc3)) * ex[k];
                if (!cur_m[k]) s = a_self;     // mask==0: carry previous alpha

                // Renorm EVERY step (f16 range) — uniform scale is exact.
                const float mx = wave_max64(s);
                s *= __builtin_amdgcn_rcpf(mx);
                log_scale += __logf(mx);
                a_self = s;
                a_pk   = pack_pair_f16(s, odd);
            }
#pragma unroll
            for (int k = 0; k < 4; ++k) {
                cur_e[k] = nxt_e[k];
                cur_m[k] = nxt_m[k];
            }
        }

        ws_alpha[bt * Cn + j] = a_self;        // alpha_256, renormed
        if (j == 0) {
            ws_lsF[bt] = log_scale;
            const int t0 = tg[0];
            const int tl = tg[mcnt - 1];
            ws_num[bt] = start_t[t0] + em0[t0] + nsum + end_t[tl];
        }
    } else {
        // expT ROW j as 32 packed f16 pairs (pair over destination state).
        half2_t w2[32];
#pragma unroll
        for (int m = 0; m < 32; ++m) {
            const float w0 = __expf(transitions[j * Cn + 2 * m]);
            const float w1 = __expf(transitions[j * Cn + 2 * m + 1]);
            w2[m] = __builtin_amdgcn_cvt_pkrtz(w0, w1);
        }

        // beta_511 = exp(end - max), <= 1.
        float lp0 = end_t[j];
        const float m0 = wave_max64(lp0);
        float log_scale = m0;
        float b_self = __expf(lp0 - m0);       // lane j holds beta[j]

        // Step s applies factor at u = 511 - s. Prefetch u = 511..508.
        float cur_e[4];
        int   cur_m[4];
#pragma unroll
        for (int k = 0; k < 4; ++k) {
            const int u = Tn - 1 - k;
            cur_e[k] = em[(size_t)u * Cn];
            cur_m[k] = mk[u];
        }

        for (int g = 0; g < 64; ++g) {
            float nxt_e[4];
            int   nxt_m[4];
#pragma unroll
            for (int k = 0; k < 4; ++k) {
                const int u = Tn - 5 - 4 * g - k;  // >= 252, always valid
                nxt_e[k] = em[(size_t)u * Cn];
                nxt_m[k] = mk[u];
            }
            float ex[4];
#pragma unroll
            for (int k = 0; k < 4; ++k) ex[k] = __expf(cur_e[k]);

#pragma unroll
            for (int k = 0; k < 4; ++k) {
                const int s_idx = 4 * g + k;
                if (s_idx < Tn / 2 - 1) {      // 255 steps
                    // wv[j] = e_u[j] * beta[j]  (<= ~200, f16-safe)
                    const float wv = b_self * ex[k];
                    const int  b_pk = pack_pair_f16(wv, odd);
                    int au[32];
#pragma unroll
                    for (int m = 0; m < 32; ++m)
                        au[m] = __builtin_amdgcn_readlane(b_pk, 2 * m);

                    float acc0 = 0.f, acc1 = 0.f, acc2 = 0.f, acc3 = 0.f;
#pragma unroll
                    for (int m = 0; m < 32; m += 4) {
                        acc0 = __builtin_amdgcn_fdot2(int_as_half2(au[m + 0]), w2[m + 0], acc0, false);
                        acc1 = __builtin_amdgcn_fdot2(int_as_half2(au[m + 1]), w2[m + 1], acc1, false);
                        acc2 = __builtin_amdgcn_fdot2(int_as_half2(au[m + 2]), w2[m + 2], acc2, false);
                        acc3 = __builtin_amdgcn_fdot2(int_as_half2(au[m + 3]), w2[m + 3], acc3, false);
                    }
                    float s = ((acc0 + acc1) + (acc2 + acc3));
                    if (!cur_m[k]) s = b_self;  // frozen step: beta carries

                    const float mx = wave_max64(s);
                    s *= __builtin_amdgcn_rcpf(mx);
                    log_scale += __logf(mx);
                    b_self = s;
                }
            }
#pragma unroll
            for (int k = 0; k < 4; ++k) {
                cur_e[k] = nxt_e[k];
                cur_m[k] = nxt_m[k];
            }
        }

        ws_beta[bt * Cn + j] = b_self;         // beta_256
        if (j == 0) ws_lsB[bt] = log_scale;
    }
}

// One block, 512 threads: thread b handles chain b fully, then block-reduce.
__global__ __launch_bounds__(512) void crf_finalize_kernel(
    const float* __restrict__ ws_alpha,
    const float* __restrict__ ws_beta,
    const float* __restrict__ ws_lsF,
    const float* __restrict__ ws_lsB,
    const float* __restrict__ ws_num,
    float*       __restrict__ out)
{
    __shared__ float sh[8];
    const int b = threadIdx.x;  // 0..511 = chain index
    float z = 0.f;
#pragma unroll
    for (int i = 0; i < Cn; ++i)
        z += ws_alpha[b * Cn + i] * ws_beta[b * Cn + i];
    float v = ws_lsF[b] + ws_lsB[b] + __logf(z) - ws_num[b];
#pragma unroll
    for (int off = 32; off > 0; off >>= 1) v += __shfl_xor(v, off, 64);
    if ((b & 63) == 0) sh[b >> 6] = v;
    __syncthreads();
    if (b == 0) {
        float s = 0.f;
#pragma unroll
        for (int k = 0; k < 8; ++k) s += sh[k];
        out[0] = s * (1.0f / Bn);
    }
}

extern "C" void kernel_launch(void* const* d_in, const int* in_sizes, int n_in,
                              void* d_out, int out_size, void* d_ws, size_t ws_size,
                              hipStream_t stream)
{
    const float* emissions   = (const float*)d_in[0];
    const int*   tags        = (const int*)d_in[1];
    const int*   mask        = (const int*)d_in[2];
    const float* transitions = (const float*)d_in[3];
    const float* start_t     = (const float*)d_in[4];
    const float* end_t       = (const float*)d_in[5];

    float* ws       = (float*)d_ws;
    float* ws_alpha = ws;                       // 512*64
    float* ws_beta  = ws_alpha + Bn * Cn;       // 512*64
    float* ws_lsF   = ws_beta + Bn * Cn;        // 512
    float* ws_lsB   = ws_lsF + Bn;              // 512
    float* ws_num   = ws_lsB + Bn;              // 512

    crf_half_kernel<<<2 * Bn, Cn, 0, stream>>>(emissions, tags, mask, transitions,
                                               start_t, end_t,
                                               ws_alpha, ws_beta, ws_lsF, ws_lsB, ws_num);
    crf_finalize_kernel<<<1, 512, 0, stream>>>(ws_alpha, ws_beta, ws_lsF, ws_lsB,
                                               ws_num, (float*)d_out);
}